// Round 8
// baseline (240.570 us; speedup 1.0000x reference)
//
#include <hip/hip_runtime.h>

#define TTOT 16384        // 4 * 4096 tokens
#define DDIM 2048
#define NEXP 64
#define TPB  32           // tokens per block
#define KCH  256          // K-chunk per wave (DDIM / 8 waves)
#define NKS  8            // k-steps per wave (KCH / 32)
#define WTERM (NEXP * DDIM)   // 131072 elems per split term

typedef __attribute__((ext_vector_type(8))) short bf16x8;
typedef __attribute__((ext_vector_type(4))) float f32x4;
typedef __attribute__((ext_vector_type(4))) unsigned int u32x4;

// ---------------------------------------------------------------------------
// Exact fp32 -> 3x bf16 truncation split (proven R3/R4). x == xh + xm + xl.
// ---------------------------------------------------------------------------
__device__ __forceinline__ void split3(const f32x4 va, const f32x4 vb,
                                       bf16x8& h, bf16x8& m, bf16x8& l)
{
    const float f[8] = {va.x, va.y, va.z, va.w, vb.x, vb.y, vb.z, vb.w};
    unsigned int hu[8], mu[8], lu[8];
#pragma unroll
    for (int j = 0; j < 8; ++j) {
        const unsigned int xb = __float_as_uint(f[j]);
        const unsigned int hb = xb & 0xffff0000u;
        const float r1 = f[j] - __uint_as_float(hb);
        const unsigned int mb = __float_as_uint(r1) & 0xffff0000u;
        const float r2 = r1 - __uint_as_float(mb);
        hu[j] = hb; mu[j] = mb; lu[j] = __float_as_uint(r2);
    }
    u32x4 hw, mw, lw;
#pragma unroll
    for (int w = 0; w < 4; ++w) {
        hw[w] = (hu[2 * w] >> 16) | (hu[2 * w + 1] & 0xffff0000u);
        mw[w] = (mu[2 * w] >> 16) | (mu[2 * w + 1] & 0xffff0000u);
        lw[w] = (lu[2 * w] >> 16) | (lu[2 * w + 1] & 0xffff0000u);
    }
    h = __builtin_bit_cast(bf16x8, hw);
    m = __builtin_bit_cast(bf16x8, mw);
    l = __builtin_bit_cast(bf16x8, lw);
}

// ---------------------------------------------------------------------------
// Prep: split W [2048][64] fp32 into W4[3][256 kg][64 e][8 d] bf16.
// ---------------------------------------------------------------------------
__global__ __launch_bounds__(256)
void w_split(const float* __restrict__ W, unsigned short* __restrict__ W4)
{
    const int q = blockIdx.x * 256 + threadIdx.x;   // 0 .. 131071
    const int e = q >> 11;                          // 0..63
    const int d = q & 2047;                         // 0..2047
    const float w = W[(size_t)d * NEXP + e];
    const unsigned int xb = __float_as_uint(w);
    const unsigned int hb = xb & 0xffff0000u;
    const float r1 = w - __uint_as_float(hb);
    const unsigned int mb = __float_as_uint(r1) & 0xffff0000u;
    const float r2 = r1 - __uint_as_float(mb);
    const unsigned int lb = __float_as_uint(r2);
    const size_t o = ((size_t)(d >> 3) * 64 + e) * 8 + (d & 7);
    W4[o]             = (unsigned short)(hb >> 16);
    W4[o + WTERM]     = (unsigned short)(mb >> 16);
    W4[o + 2 * WTERM] = (unsigned short)(lb >> 16);
}

// ---------------------------------------------------------------------------
// GEMM (R4 base + T4 counted-vmcnt): 512 blocks x 512 thr (8 waves). Wave wq
// owns K-chunk [wq*256, +256) for the block's 32 tokens x 64 experts. x is
// staged per-wave per-k-step into a PRIVATE 4KB LDS sub-tile via
// global_load_lds (double-buffered, granule-XOR-swizzled via pre-swizzled
// global source). Per k-step: issue STAGE(ks+1) [4 ops] + B(ks) loads
// [12 ops], then s_waitcnt vmcnt(16) -- waits only for STAGE(ks) to land,
// keeps the 16 just-issued ops in flight (NEVER drains to 0 in the loop;
// m218: drain-0 == no pipeline). sched_barrier(0) fences compiler motion
// (rule 18). No block barriers in the loop: waves fully decoupled.
// Arithmetic bit-identical to R4 (same split, same MFMA order, same combine)
// -> absmax must be 0.0002441406.
// ---------------------------------------------------------------------------
__global__ __launch_bounds__(512, 4)
void moe_gemm(const float* __restrict__ x, const unsigned short* __restrict__ W4,
              float* __restrict__ out)
{
    __shared__ float xs[2][8][32][32];   // 64 KB: [buf][wave][token][d]
    __shared__ float L[TPB][NEXP + 1];   // 8.3 KB combine buffer
    const int tid  = threadIdx.x;
    const int lane = tid & 63;
    const int wq   = __builtin_amdgcn_readfirstlane(tid >> 6);  // 0..7
    const int lrow = lane & 15;          // A row (token) / B col (expert)
    const int lk   = lane >> 4;          // k-group (0..3)
    const int tokBase = blockIdx.x * TPB;
    const int kBase   = wq * KCH;

    f32x4 c[2][4];
#pragma unroll
    for (int mt = 0; mt < 2; ++mt)
#pragma unroll
        for (int nt = 0; nt < 4; ++nt)
            c[mt][nt] = (f32x4){0.0f, 0.0f, 0.0f, 0.0f};

    // stage-side map (R4-proven): phys granule p=lane&7 of row lane>>3 gets
    // logical granule (lane&7)^(lane>>3); LDS dest linear.
    const int srow = lane >> 3;
    const int scol = (lane & 7) ^ srow;
    const float* sBase = x + (size_t)(tokBase + srow) * DDIM + kBase + scol * 4;

#define STAGE(ksn, dstbuf)                                                     \
    {                                                                          \
        const float* g_ = sBase + (ksn) * 32;                                  \
        float* l_ = &xs[dstbuf][wq][0][0];                                     \
        _Pragma("unroll")                                                      \
        for (int cc = 0; cc < 4; ++cc)                                         \
            __builtin_amdgcn_global_load_lds(                                  \
                (const __attribute__((address_space(1))) unsigned int*)        \
                    (g_ + cc * 8 * DDIM),                                      \
                (__attribute__((address_space(3))) unsigned int*)              \
                    (l_ + cc * 256), 16, 0, 0);                                \
    }

    // read-side map: logical granule lk*2 lives at phys (lk*2)^(row&7)
    const int ph    = (lk * 2) ^ (lrow & 7);
    const int aoff0 = lrow * 32 + ph * 4;
    const int aoff1 = (16 + lrow) * 32 + ph * 4;

    // B pointers (L2-resident W4)
    const unsigned short* bph = W4 + (size_t)(((kBase >> 3) + lk) * 512 + lrow * 8);
    const unsigned short* bpm = bph + WTERM;
    const unsigned short* bpl = bpm + WTERM;

    // prologue: stage k-step 0 into buf 0
    STAGE(0, 0)

#pragma unroll 2
    for (int ks = 0; ks < NKS; ++ks) {
        const int buf = ks & 1;

        // issue next stage (4 vmem) then this step's B loads (12 vmem),
        // THEN a counted wait: >=16 outstanding allowed = everything just
        // issued stays in flight; only STAGE(ks) (older) must have landed.
        bf16x8 bh[4], bm[4], bl[4];
        if (ks + 1 < NKS) {
            STAGE(ks + 1, buf ^ 1)
#pragma unroll
            for (int nt = 0; nt < 4; ++nt) {
                bh[nt] = *(const bf16x8*)(bph + ks * 2048 + nt * 128);
                bm[nt] = *(const bf16x8*)(bpm + ks * 2048 + nt * 128);
                bl[nt] = *(const bf16x8*)(bpl + ks * 2048 + nt * 128);
            }
            asm volatile("s_waitcnt vmcnt(16)" ::: "memory");
        } else {
#pragma unroll
            for (int nt = 0; nt < 4; ++nt) {
                bh[nt] = *(const bf16x8*)(bph + ks * 2048 + nt * 128);
                bm[nt] = *(const bf16x8*)(bpm + ks * 2048 + nt * 128);
                bl[nt] = *(const bf16x8*)(bpl + ks * 2048 + nt * 128);
            }
            asm volatile("s_waitcnt vmcnt(12)" ::: "memory");
        }
        __builtin_amdgcn_sched_barrier(0);

        // A from LDS (swizzled read), then exact 3-way split
        const float* sub = &xs[buf][wq][0][0];
        const f32x4 c0a = *(const f32x4*)(sub + aoff0);
        const f32x4 c0b = *(const f32x4*)(sub + (aoff0 ^ 4));
        const f32x4 c1a = *(const f32x4*)(sub + aoff1);
        const f32x4 c1b = *(const f32x4*)(sub + (aoff1 ^ 4));
        bf16x8 ah0, am0, al0, ah1, am1, al1;
        split3(c0a, c0b, ah0, am0, al0);
        split3(c1a, c1b, ah1, am1, al1);

        // 6 passes x 2 M x 4 N = 48 MFMA (verbatim R3/R4 order)
#pragma unroll
        for (int nt = 0; nt < 4; ++nt) c[0][nt] = __builtin_amdgcn_mfma_f32_16x16x32_bf16(ah0, bh[nt], c[0][nt], 0, 0, 0);
#pragma unroll
        for (int nt = 0; nt < 4; ++nt) c[1][nt] = __builtin_amdgcn_mfma_f32_16x16x32_bf16(ah1, bh[nt], c[1][nt], 0, 0, 0);
#pragma unroll
        for (int nt = 0; nt < 4; ++nt) c[0][nt] = __builtin_amdgcn_mfma_f32_16x16x32_bf16(ah0, bm[nt], c[0][nt], 0, 0, 0);
#pragma unroll
        for (int nt = 0; nt < 4; ++nt) c[1][nt] = __builtin_amdgcn_mfma_f32_16x16x32_bf16(ah1, bm[nt], c[1][nt], 0, 0, 0);
#pragma unroll
        for (int nt = 0; nt < 4; ++nt) c[0][nt] = __builtin_amdgcn_mfma_f32_16x16x32_bf16(am0, bh[nt], c[0][nt], 0, 0, 0);
#pragma unroll
        for (int nt = 0; nt < 4; ++nt) c[1][nt] = __builtin_amdgcn_mfma_f32_16x16x32_bf16(am1, bh[nt], c[1][nt], 0, 0, 0);
#pragma unroll
        for (int nt = 0; nt < 4; ++nt) c[0][nt] = __builtin_amdgcn_mfma_f32_16x16x32_bf16(ah0, bl[nt], c[0][nt], 0, 0, 0);
#pragma unroll
        for (int nt = 0; nt < 4; ++nt) c[1][nt] = __builtin_amdgcn_mfma_f32_16x16x32_bf16(ah1, bl[nt], c[1][nt], 0, 0, 0);
#pragma unroll
        for (int nt = 0; nt < 4; ++nt) c[0][nt] = __builtin_amdgcn_mfma_f32_16x16x32_bf16(al0, bh[nt], c[0][nt], 0, 0, 0);
#pragma unroll
        for (int nt = 0; nt < 4; ++nt) c[1][nt] = __builtin_amdgcn_mfma_f32_16x16x32_bf16(al1, bh[nt], c[1][nt], 0, 0, 0);
#pragma unroll
        for (int nt = 0; nt < 4; ++nt) c[0][nt] = __builtin_amdgcn_mfma_f32_16x16x32_bf16(am0, bm[nt], c[0][nt], 0, 0, 0);
#pragma unroll
        for (int nt = 0; nt < 4; ++nt) c[1][nt] = __builtin_amdgcn_mfma_f32_16x16x32_bf16(am1, bm[nt], c[1][nt], 0, 0, 0);
    }
#undef STAGE

    // combine the 8 waves' fp32 K-chunk partials in LDS (one-time, proven)
    for (int w = 0; w < 8; ++w) {
        if (wq == w) {
#pragma unroll
            for (int mt = 0; mt < 2; ++mt)
#pragma unroll
                for (int nt = 0; nt < 4; ++nt)
#pragma unroll
                    for (int i = 0; i < 4; ++i) {
                        const int row = mt * 16 + lk * 4 + i;  // token in block
                        const int col = nt * 16 + lrow;        // expert
                        if (w == 0) L[row][col]  = c[mt][nt][i];
                        else        L[row][col] += c[mt][nt][i];
                    }
        }
        __syncthreads();
    }

    float* dispatch = out;
    float* probs    = out + (size_t)TTOT * NEXP;
    float* tkp      = out + (size_t)2 * TTOT * NEXP;
    float* tki      = tkp + (size_t)TTOT * 2;

    // each wave: softmax + top-2 for 4 tokens, lane = expert (proven code)
#pragma unroll
    for (int tt = 0; tt < 4; ++tt) {
        const int te = wq * 4 + tt;
        const int gt = tokBase + te;
        const float Lg = L[te][lane];

        float m = Lg;
#pragma unroll
        for (int off = 32; off; off >>= 1) m = fmaxf(m, __shfl_xor(m, off, 64));
        const float p = expf(Lg - m);
        float sden = p;
#pragma unroll
        for (int off = 32; off; off >>= 1) sden += __shfl_xor(sden, off, 64);
        const float prob = p / sden;

        // top-1 (ties -> lowest index, matching lax.top_k / np)
        float v1 = prob; int i1 = lane;
#pragma unroll
        for (int off = 32; off; off >>= 1) {
            const float ov = __shfl_xor(v1, off, 64);
            const int   oi = __shfl_xor(i1, off, 64);
            if (ov > v1 || (ov == v1 && oi < i1)) { v1 = ov; i1 = oi; }
        }
        // top-2
        float v2 = (lane == i1) ? -1.0f : prob; int i2 = lane;
#pragma unroll
        for (int off = 32; off; off >>= 1) {
            const float ov = __shfl_xor(v2, off, 64);
            const int   oi = __shfl_xor(i2, off, 64);
            if (ov > v2 || (ov == v2 && oi < i2)) { v2 = ov; i2 = oi; }
        }

        probs[(size_t)gt * NEXP + lane]    = prob;
        dispatch[(size_t)gt * NEXP + lane] = (lane == i1 || lane == i2) ? 1.0f : 0.0f;
        if (lane == 0) {
            tkp[(size_t)gt * 2 + 0] = v1;
            tkp[(size_t)gt * 2 + 1] = v2;
            tki[(size_t)gt * 2 + 0] = (float)i1;
            tki[(size_t)gt * 2 + 1] = (float)i2;
        }
    }
}

extern "C" void kernel_launch(void* const* d_in, const int* in_sizes, int n_in,
                              void* d_out, int out_size, void* d_ws, size_t ws_size,
                              hipStream_t stream) {
    const float* x = (const float*)d_in[0];
    const float* W = (const float*)d_in[1];
    float* out = (float*)d_out;
    unsigned short* W4 = (unsigned short*)d_ws;   // 3 * 131072 * 2B = 768 KB

    w_split<<<512, 256, 0, stream>>>(W, W4);
    moe_gemm<<<TTOT / TPB, 512, 0, stream>>>(x, W4, out);
}